// Round 1
// baseline (2126.428 us; speedup 1.0000x reference)
//
#include <hip/hip_runtime.h>
#include <cstdint>
#include <cstddef>
#include <math.h>

#define M_ROWS 16384
#define N_COLS 1000
#define K_DIM  4096
#define NUM_TTA 64
#define KEPT 6
#define BATCH 256

#define BM 256
#define BN 128
#define BK 16
#define TM 16
#define TN 8

// ---------------- GEMM: logits = x @ W + b (fp32, VALU) ----------------
// block = 256 threads = 16(tx: n) x 16(ty: m); per-thread 16x8 register tile.
// B-fragment is split into two groups of 4 cols (tx*4 and 64+tx*4) so LDS
// reads are <=2-way bank aliased (free). A staged transposed k-major.
__global__ __launch_bounds__(256, 2)
void gemm_f32(const float* __restrict__ A, const float* __restrict__ Wm,
              const float* __restrict__ bias, float* __restrict__ logits,
              int m_base)
{
    __shared__ float As[BK][BM + 4];   // stride 260 words (1040B, 16B-aligned rows)
    __shared__ float Bs[BK][BN + 4];   // stride 132 words (528B, 16B-aligned rows)

    const int tid = threadIdx.x;
    const int tx = tid & 15;
    const int ty = tid >> 4;
    const int n0 = blockIdx.x * BN;
    const int row_local0 = blockIdx.y * BM;
    const int m0 = m_base + row_local0;

    float acc[TM][TN];
#pragma unroll
    for (int i = 0; i < TM; ++i)
#pragma unroll
        for (int j = 0; j < TN; ++j) acc[i][j] = 0.f;

    const int ar  = tid >> 2;          // 0..63  (A row within quarter)
    const int akq = (tid & 3) << 2;    // 0,4,8,12 (k quad)
    const int bk0 = tid >> 5;          // 0..7
    const int bn4 = (tid & 31) << 2;   // 0..124

    for (int k0 = 0; k0 < K_DIM; k0 += BK) {
        // ---- stage A tile (256 x 16), transpose to As[k][m] ----
#pragma unroll
        for (int i = 0; i < 4; ++i) {
            const int r = ar + 64 * i;
            const float4 v = *(const float4*)(A + (size_t)(m0 + r) * K_DIM + k0 + akq);
            As[akq + 0][r] = v.x;
            As[akq + 1][r] = v.y;
            As[akq + 2][r] = v.z;
            As[akq + 3][r] = v.w;
        }
        // ---- stage B tile (16 x 128), mask n >= 1000 ----
#pragma unroll
        for (int i = 0; i < 2; ++i) {
            const int kk = bk0 + 8 * i;
            const int n = n0 + bn4;
            const size_t base = (size_t)(k0 + kk) * N_COLS;
            float4 v;
            if (n + 3 < N_COLS) {
                v = *(const float4*)(Wm + base + n);
            } else {
                v.x = (n + 0 < N_COLS) ? Wm[base + n + 0] : 0.f;
                v.y = (n + 1 < N_COLS) ? Wm[base + n + 1] : 0.f;
                v.z = (n + 2 < N_COLS) ? Wm[base + n + 2] : 0.f;
                v.w = (n + 3 < N_COLS) ? Wm[base + n + 3] : 0.f;
            }
            *(float4*)&Bs[kk][bn4] = v;
        }
        __syncthreads();

#pragma unroll 4
        for (int kk = 0; kk < BK; ++kk) {
            float a[TM], b[TN];
#pragma unroll
            for (int i = 0; i < 4; ++i)
                *(float4*)&a[4 * i] = *(const float4*)&As[kk][ty * TM + 4 * i];
            *(float4*)&b[0] = *(const float4*)&Bs[kk][tx * 4];
            *(float4*)&b[4] = *(const float4*)&Bs[kk][64 + tx * 4];
#pragma unroll
            for (int i = 0; i < TM; ++i)
#pragma unroll
                for (int j = 0; j < TN; ++j)
                    acc[i][j] = fmaf(a[i], b[j], acc[i][j]);
        }
        __syncthreads();
    }

    // ---- epilogue: + bias, store (cols tx*4 and 64+tx*4) ----
#pragma unroll
    for (int i = 0; i < TM; ++i) {
        const int rl = row_local0 + ty * TM + i;
        const size_t rowoff = (size_t)rl * N_COLS;
#pragma unroll
        for (int g = 0; g < 2; ++g) {
            const int n = n0 + g * 64 + tx * 4;
            if (n + 3 < N_COLS) {
                float4 o;
                o.x = acc[i][g * 4 + 0] + bias[n + 0];
                o.y = acc[i][g * 4 + 1] + bias[n + 1];
                o.z = acc[i][g * 4 + 2] + bias[n + 2];
                o.w = acc[i][g * 4 + 3] + bias[n + 3];
                *(float4*)(logits + rowoff + n) = o;
            } else {
#pragma unroll
                for (int j = 0; j < 4; ++j)
                    if (n + j < N_COLS)
                        logits[rowoff + n + j] = acc[i][g * 4 + j] + bias[n + j];
            }
        }
    }
}

// ------------- per-view softmax stats: entropy (f64 accum) + argmax -------------
__global__ __launch_bounds__(256)
void row_stats(const float* __restrict__ logits, double* __restrict__ ent,
               int* __restrict__ votes, int v_base)
{
    __shared__ float  srow[N_COLS];
    __shared__ float  redv[256];
    __shared__ int    redi[256];
    __shared__ double redS[256];
    __shared__ double redT[256];

    const int t = threadIdx.x;
    const float* row = logits + (size_t)blockIdx.x * N_COLS;

    float bv = -3.0e38f;
    int bi = 0;
    for (int c = t; c < N_COLS; c += 256) {
        const float x = row[c];
        srow[c] = x;
        if (x > bv) { bv = x; bi = c; }   // strict > keeps first index per thread
    }
    redv[t] = bv; redi[t] = bi;
    __syncthreads();
    for (int s = 128; s > 0; s >>= 1) {
        if (t < s) {
            const float ov = redv[t + s]; const int oi = redi[t + s];
            if (ov > redv[t] || (ov == redv[t] && oi < redi[t])) { redv[t] = ov; redi[t] = oi; }
        }
        __syncthreads();
    }
    const float mx  = redv[0];
    const int amax  = redi[0];

    double S = 0.0, T = 0.0;
    for (int c = t; c < N_COLS; c += 256) {
        const float d = srow[c] - mx;      // fp32 like reference softmax
        const double e = exp((double)d);   // f64 accumulation kills ordering noise
        S += e; T += e * (double)d;
    }
    redS[t] = S; redT[t] = T;
    __syncthreads();
    for (int s = 128; s > 0; s >>= 1) {
        if (t < s) { redS[t] += redS[t + s]; redT[t] += redT[t + s]; }
        __syncthreads();
    }
    if (t == 0) {
        const double Sf = redS[0], Tf = redT[0];
        ent[v_base + blockIdx.x]   = log(Sf) - Tf / Sf;   // H = logS - T/S
        votes[v_base + blockIdx.x] = amax;
    }
}

// ------------- per-batch voting: stable sort by entropy, tie loop -------------
__global__ __launch_bounds__(64)
void vote_kernel(const double* __restrict__ ent, const int* __restrict__ votes,
                 float* __restrict__ out)
{
    __shared__ double e[NUM_TTA];
    __shared__ int    sv[NUM_TTA];
    __shared__ float  counts[N_COLS];

    const int b = blockIdx.x;
    const int t = threadIdx.x;

    e[t] = ent[b * NUM_TTA + t];
    const int myv = votes[b * NUM_TTA + t];
    for (int c = t; c < N_COLS; c += NUM_TTA) counts[c] = 0.f;
    __syncthreads();

    // stable rank (ascending entropy, index breaks ties) == jnp.argsort
    const double et = e[t];
    int rank = 0;
#pragma unroll
    for (int i = 0; i < NUM_TTA; ++i) {
        const double ei = e[i];
        rank += (ei < et) || (ei == et && i < t);
    }
    sv[rank] = myv;
    __syncthreads();

    if (t == 0) {
        // initial histogram of the 6 most-confident votes
        for (int j = 0; j < KEPT; ++j) counts[sv[j]] += 1.f;
        // M, Tc over nonzero classes (only classes among sv[0..5])
        float Mv = 0.f; int Tc = 0;
        for (int j = 0; j < KEPT; ++j) {
            const int c = sv[j];
            bool dup = false;
            for (int q = 0; q < j; ++q) dup = dup || (sv[q] == c);
            if (dup) continue;
            const float cv = counts[c];
            if (cv > Mv) { Mv = cv; Tc = 1; }
            else if (cv == Mv) { Tc += 1; }
        }
        // fori_loop: once untied, counts never change again -> early exit
        for (int i = 0; i < NUM_TTA - KEPT; ++i) {
            if (Tc <= 1) break;
            const int c = sv[KEPT + i];
            const float oldc = counts[c];
            counts[c] = oldc + 1.f;
            if (oldc == Mv)            { Mv += 1.f; Tc = 1; }
            else if (oldc + 1.f == Mv) { Tc += 1; }
        }
    }
    __syncthreads();

    const size_t o0 = (size_t)b * N_COLS;
    for (int c = t; c < N_COLS; c += NUM_TTA)
        out[o0 + c] = logf(counts[c] * (1.f / 64.f) + 1e-8f);
}

// -------------------------------- launch --------------------------------
extern "C" void kernel_launch(void* const* d_in, const int* in_sizes, int n_in,
                              void* d_out, int out_size, void* d_ws, size_t ws_size,
                              hipStream_t stream) {
    const float* x    = (const float*)d_in[0];
    const float* Wm   = (const float*)d_in[1];
    const float* bias = (const float*)d_in[2];
    float* out = (float*)d_out;

    // ws layout: ent (16384 f64) | votes (16384 i32) | logits chunk (f32)
    double* ent  = (double*)d_ws;
    int*   votes = (int*)((char*)d_ws + (size_t)M_ROWS * 8);
    float* logits = (float*)((char*)d_ws + (size_t)M_ROWS * 8 + (size_t)M_ROWS * 4);
    const size_t reserved = (size_t)M_ROWS * 12;
    size_t avail = (ws_size > reserved) ? (ws_size - reserved) : 0;

    long long max_rows = (long long)(avail / ((size_t)N_COLS * 4));
    long long chunk = (max_rows / BM) * BM;
    if (chunk > M_ROWS) chunk = M_ROWS;
    if (chunk < BM) chunk = BM;   // trust ws_size is at least ~1MB

    for (int m0 = 0; m0 < M_ROWS; m0 += (int)chunk) {
        int rows = (int)((M_ROWS - m0 < chunk) ? (M_ROWS - m0) : chunk);
        dim3 grid(N_COLS / BN + 1, rows / BM);   // 8 n-tiles x (rows/256) m-tiles
        gemm_f32<<<grid, 256, 0, stream>>>(x, Wm, bias, logits, m0);
        row_stats<<<rows, 256, 0, stream>>>(logits, ent, votes, m0);
    }
    vote_kernel<<<BATCH, NUM_TTA, 0, stream>>>(ent, votes, out);
}

// Round 2
// 1060.284 us; speedup vs baseline: 2.0055x; 2.0055x over previous
//
#include <hip/hip_runtime.h>
#include <cstdint>
#include <cstddef>
#include <math.h>

#define M_ROWS 16384
#define N_COLS 1000
#define N_PAD  1024
#define K_DIM  4096
#define NUM_TTA 64
#define KEPT 6
#define BATCH 256
#define CHUNK_MAX 8192

typedef __attribute__((ext_vector_type(8))) short short8;
typedef __attribute__((ext_vector_type(4))) float v4f;

#define GL_LDS16(g, l)                                                        \
    __builtin_amdgcn_global_load_lds(                                         \
        (const __attribute__((address_space(1))) unsigned int*)(g),           \
        (__attribute__((address_space(3))) unsigned int*)(l), 16, 0, 0)

// ---- exact round-to-nearest-even bf16 split: x = hi + lo (+ ~2^-18 rel) ----
__device__ __forceinline__ unsigned short bf_rn(float x) {
    unsigned int u = __float_as_uint(x);
    return (unsigned short)((u + 0x7fffu + ((u >> 16) & 1u)) >> 16);
}
__device__ __forceinline__ void split2(float x, unsigned short& h, unsigned short& l) {
    h = bf_rn(x);
    float hf = __uint_as_float(((unsigned int)h) << 16);
    l = bf_rn(x - hf);
}

// ---------------- W: transpose 4096x1000 -> [n][k] 1024x4096, split ----------------
__global__ __launch_bounds__(1024)
void split_w(const float* __restrict__ W, unsigned short* __restrict__ Wh,
             unsigned short* __restrict__ Wl)
{
    __shared__ float tile[32][33];
    const int k0 = blockIdx.x * 32, n0 = blockIdx.y * 32;
    const int tx = threadIdx.x, ty = threadIdx.y;
    const int n = n0 + tx, k = k0 + ty;
    tile[ty][tx] = (n < N_COLS) ? W[(size_t)k * N_COLS + n] : 0.f;
    __syncthreads();
    const float w = tile[tx][ty];           // = W[k0+tx][n0+ty]
    unsigned short h, l;
    split2(w, h, l);
    const size_t o = (size_t)(n0 + ty) * K_DIM + k0 + tx;
    Wh[o] = h; Wl[o] = l;
}

// ---------------- A: split fp32 chunk -> hi/lo bf16 (same layout) ----------------
__global__ __launch_bounds__(256)
void split_a(const float* __restrict__ x, unsigned short* __restrict__ Ah,
             unsigned short* __restrict__ Al, long long nelem)
{
    const long long i = ((long long)blockIdx.x * 256 + threadIdx.x) * 4;
    if (i >= nelem) return;
    const float4 v = *(const float4*)(x + i);
    unsigned short h0, h1, h2, h3, l0, l1, l2, l3;
    split2(v.x, h0, l0); split2(v.y, h1, l1);
    split2(v.z, h2, l2); split2(v.w, h3, l3);
    ushort4 hv = {h0, h1, h2, h3}, lv = {l0, l1, l2, l3};
    *(ushort4*)(Ah + i) = hv;
    *(ushort4*)(Al + i) = lv;
}

// ------------- GEMM: logits = A @ Wt^T + b via bf16 split-2 MFMA -------------
// 128x128 block tile, 256 thr = 4 waves each 64x64, 16x16x32 MFMA, BK=32.
__global__ __launch_bounds__(256, 2)
void gemm_mfma(const unsigned short* __restrict__ Ah, const unsigned short* __restrict__ Al,
               const unsigned short* __restrict__ Bh, const unsigned short* __restrict__ Bl,
               const float* __restrict__ bias, float* __restrict__ logits)
{
    __shared__ short sAh[128 * 32];
    __shared__ short sAl[128 * 32];
    __shared__ short sBh[128 * 32];
    __shared__ short sBl[128 * 32];

    const int t = threadIdx.x;
    const int lane = t & 63;
    const int wave = t >> 6;
    const int ml = lane & 15;          // m (or n) within 16-tile
    const int half = lane >> 4;        // 0..3 -> k-quarter of 32
    const int wm = (wave >> 1) * 64, wn = (wave & 1) * 64;
    const int n0 = blockIdx.x * 128;
    const int m0 = blockIdx.y * 128;

    v4f acc[4][4];
#pragma unroll
    for (int i = 0; i < 4; ++i)
#pragma unroll
        for (int j = 0; j < 4; ++j) acc[i][j] = (v4f){0.f, 0.f, 0.f, 0.f};

    // staging map: lds byte t*16 (+4096) -> row r0(+64), byte-in-row kb0
    const int r0 = t >> 2;
    const int kb0 = (t & 3) * 16;
    const char* pAh = (const char*)Ah + (size_t)(m0 + r0) * (K_DIM * 2) + kb0;
    const char* pAl = (const char*)Al + (size_t)(m0 + r0) * (K_DIM * 2) + kb0;
    const char* pBh = (const char*)Bh + (size_t)(n0 + r0) * (K_DIM * 2) + kb0;
    const char* pBl = (const char*)Bl + (size_t)(n0 + r0) * (K_DIM * 2) + kb0;
    short* lAh = sAh + t * 8;  short* lAl = sAl + t * 8;
    short* lBh = sBh + t * 8;  short* lBl = sBl + t * 8;
    const size_t rstep = (size_t)64 * K_DIM * 2;   // +64 rows in bytes

    for (int kb = 0; kb < K_DIM * 2; kb += 64) {   // 32 k-values = 64 bytes / step
        GL_LDS16(pAh + kb, lAh);  GL_LDS16(pAh + rstep + kb, lAh + 2048);
        GL_LDS16(pAl + kb, lAl);  GL_LDS16(pAl + rstep + kb, lAl + 2048);
        GL_LDS16(pBh + kb, lBh);  GL_LDS16(pBh + rstep + kb, lBh + 2048);
        GL_LDS16(pBl + kb, lBl);  GL_LDS16(pBl + rstep + kb, lBl + 2048);
        __syncthreads();

        short8 ah[4], al[4], bh[4], bl[4];
#pragma unroll
        for (int i = 0; i < 4; ++i) {
            ah[i] = *(const short8*)&sAh[(wm + i * 16 + ml) * 32 + half * 8];
            al[i] = *(const short8*)&sAl[(wm + i * 16 + ml) * 32 + half * 8];
            bh[i] = *(const short8*)&sBh[(wn + i * 16 + ml) * 32 + half * 8];
            bl[i] = *(const short8*)&sBl[(wn + i * 16 + ml) * 32 + half * 8];
        }
#pragma unroll
        for (int i = 0; i < 4; ++i)
#pragma unroll
            for (int j = 0; j < 4; ++j) {
                acc[i][j] = __builtin_amdgcn_mfma_f32_16x16x32_bf16(ah[i], bl[j], acc[i][j], 0, 0, 0);
                acc[i][j] = __builtin_amdgcn_mfma_f32_16x16x32_bf16(al[i], bh[j], acc[i][j], 0, 0, 0);
                acc[i][j] = __builtin_amdgcn_mfma_f32_16x16x32_bf16(ah[i], bh[j], acc[i][j], 0, 0, 0);
            }
        __syncthreads();
    }

    // epilogue: C/D layout col = lane&15, row = (lane>>4)*4 + reg  [m89/m91]
#pragma unroll
    for (int i = 0; i < 4; ++i) {
        const int rbase = m0 + wm + i * 16 + half * 4;
#pragma unroll
        for (int j = 0; j < 4; ++j) {
            const int col = n0 + wn + j * 16 + ml;
            if (col < N_COLS) {
                const float bv = bias[col];
#pragma unroll
                for (int r = 0; r < 4; ++r)
                    logits[(size_t)(rbase + r) * N_COLS + col] = acc[i][j][r] + bv;
            }
        }
    }
}

// ------------- per-view softmax stats: entropy (f64 accum) + argmax -------------
__global__ __launch_bounds__(256)
void row_stats(const float* __restrict__ logits, double* __restrict__ ent,
               int* __restrict__ votes, int v_base)
{
    __shared__ float  srow[N_COLS];
    __shared__ float  redv[256];
    __shared__ int    redi[256];
    __shared__ double redS[256];
    __shared__ double redT[256];

    const int t = threadIdx.x;
    const float* row = logits + (size_t)blockIdx.x * N_COLS;

    float bv = -3.0e38f;
    int bi = 0;
    for (int c = t; c < N_COLS; c += 256) {
        const float x = row[c];
        srow[c] = x;
        if (x > bv) { bv = x; bi = c; }
    }
    redv[t] = bv; redi[t] = bi;
    __syncthreads();
    for (int s = 128; s > 0; s >>= 1) {
        if (t < s) {
            const float ov = redv[t + s]; const int oi = redi[t + s];
            if (ov > redv[t] || (ov == redv[t] && oi < redi[t])) { redv[t] = ov; redi[t] = oi; }
        }
        __syncthreads();
    }
    const float mx = redv[0];
    const int amax = redi[0];

    double S = 0.0, T = 0.0;
    for (int c = t; c < N_COLS; c += 256) {
        const float d = srow[c] - mx;
        const double e = exp((double)d);
        S += e; T += e * (double)d;
    }
    redS[t] = S; redT[t] = T;
    __syncthreads();
    for (int s = 128; s > 0; s >>= 1) {
        if (t < s) { redS[t] += redS[t + s]; redT[t] += redT[t + s]; }
        __syncthreads();
    }
    if (t == 0) {
        const double Sf = redS[0], Tf = redT[0];
        ent[v_base + blockIdx.x]   = log(Sf) - Tf / Sf;
        votes[v_base + blockIdx.x] = amax;
    }
}

// ------------- per-batch voting: stable sort by entropy, tie loop -------------
__global__ __launch_bounds__(64)
void vote_kernel(const double* __restrict__ ent, const int* __restrict__ votes,
                 float* __restrict__ out)
{
    __shared__ double e[NUM_TTA];
    __shared__ int    sv[NUM_TTA];
    __shared__ float  counts[N_COLS];

    const int b = blockIdx.x;
    const int t = threadIdx.x;

    e[t] = ent[b * NUM_TTA + t];
    const int myv = votes[b * NUM_TTA + t];
    for (int c = t; c < N_COLS; c += NUM_TTA) counts[c] = 0.f;
    __syncthreads();

    const double et = e[t];
    int rank = 0;
#pragma unroll
    for (int i = 0; i < NUM_TTA; ++i) {
        const double ei = e[i];
        rank += (ei < et) || (ei == et && i < t);
    }
    sv[rank] = myv;
    __syncthreads();

    if (t == 0) {
        for (int j = 0; j < KEPT; ++j) counts[sv[j]] += 1.f;
        float Mv = 0.f; int Tc = 0;
        for (int j = 0; j < KEPT; ++j) {
            const int c = sv[j];
            bool dup = false;
            for (int q = 0; q < j; ++q) dup = dup || (sv[q] == c);
            if (dup) continue;
            const float cv = counts[c];
            if (cv > Mv) { Mv = cv; Tc = 1; }
            else if (cv == Mv) { Tc += 1; }
        }
        for (int i = 0; i < NUM_TTA - KEPT; ++i) {
            if (Tc <= 1) break;
            const int c = sv[KEPT + i];
            const float oldc = counts[c];
            counts[c] = oldc + 1.f;
            if (oldc == Mv)            { Mv += 1.f; Tc = 1; }
            else if (oldc + 1.f == Mv) { Tc += 1; }
        }
    }
    __syncthreads();

    const size_t o0 = (size_t)b * N_COLS;
    for (int c = t; c < N_COLS; c += NUM_TTA)
        out[o0 + c] = logf(counts[c] * (1.f / 64.f) + 1e-8f);
}

// -------------------------------- launch --------------------------------
extern "C" void kernel_launch(void* const* d_in, const int* in_sizes, int n_in,
                              void* d_out, int out_size, void* d_ws, size_t ws_size,
                              hipStream_t stream) {
    const float* x    = (const float*)d_in[0];
    const float* Wm   = (const float*)d_in[1];
    const float* bias = (const float*)d_in[2];
    float* out = (float*)d_out;

    // ws layout: ent f64[16384] | votes i32[16384] | Wh,Wl bf16[1024*4096]
    //            | per-chunk: Ah,Al bf16[R*4096], logits f32[R*1000]
    char* p = (char*)d_ws;
    double* ent  = (double*)p;                     p += (size_t)M_ROWS * 8;
    int*   votes = (int*)p;                        p += (size_t)M_ROWS * 4;
    unsigned short* Wh = (unsigned short*)p;       p += (size_t)N_PAD * K_DIM * 2;
    unsigned short* Wl = (unsigned short*)p;       p += (size_t)N_PAD * K_DIM * 2;
    const size_t base = (size_t)(p - (char*)d_ws);

    long long R = 0;
    if (ws_size > base) R = (long long)((ws_size - base) / (size_t)(8192 + 8192 + 4000));
    R = (R / 128) * 128;
    if (R > CHUNK_MAX) R = CHUNK_MAX;
    if (R < 128) R = 128;   // ws_size >= ~20 MB assumed (known >= 66 MB from R1)

    unsigned short* Ah = (unsigned short*)p;
    unsigned short* Al = Ah + (size_t)R * K_DIM;
    float* logits = (float*)(Al + (size_t)R * K_DIM);

    split_w<<<dim3(K_DIM / 32, N_PAD / 32), dim3(32, 32), 0, stream>>>(Wm, Wh, Wl);

    for (int m0 = 0; m0 < M_ROWS; m0 += (int)R) {
        const int rows = (int)(((long long)(M_ROWS - m0) < R) ? (M_ROWS - m0) : R);
        const long long nel = (long long)rows * K_DIM;
        split_a<<<(int)((nel / 4 + 255) / 256), 256, 0, stream>>>(
            x + (size_t)m0 * K_DIM, Ah, Al, nel);
        gemm_mfma<<<dim3(N_PAD / 128, rows / 128), 256, 0, stream>>>(
            Ah, Al, Wh, Wl, bias, logits);
        row_stats<<<rows, 256, 0, stream>>>(logits, ent, votes, m0);
    }
    vote_kernel<<<BATCH, NUM_TTA, 0, stream>>>(ent, votes, out);
}

// Round 3
// 823.836 us; speedup vs baseline: 2.5811x; 1.2870x over previous
//
#include <hip/hip_runtime.h>
#include <cstdint>
#include <cstddef>
#include <math.h>

#define M_ROWS 16384
#define N_COLS 1000
#define N_PAD  1024
#define K_DIM  4096
#define NUM_TTA 64
#define KEPT 6
#define BATCH 256
#define CHUNK_MAX 16384
#define N_TILES 8          // N_PAD / 128

typedef __attribute__((ext_vector_type(8))) short short8;
typedef __attribute__((ext_vector_type(4))) float v4f;

#define GL_LDS16(g, l)                                                        \
    __builtin_amdgcn_global_load_lds(                                         \
        (const __attribute__((address_space(1))) unsigned int*)(g),           \
        (__attribute__((address_space(3))) unsigned int*)(l), 16, 0, 0)

// ---- exact round-to-nearest-even bf16 split: x = hi + lo (+ ~2^-18 rel) ----
__device__ __forceinline__ unsigned short bf_rn(float x) {
    unsigned int u = __float_as_uint(x);
    return (unsigned short)((u + 0x7fffu + ((u >> 16) & 1u)) >> 16);
}
__device__ __forceinline__ void split2(float x, unsigned short& h, unsigned short& l) {
    h = bf_rn(x);
    float hf = __uint_as_float(((unsigned int)h) << 16);
    l = bf_rn(x - hf);
}

// ---------------- W: transpose 4096x1000 -> [n][k] 1024x4096, split ----------------
__global__ __launch_bounds__(1024)
void split_w(const float* __restrict__ W, unsigned short* __restrict__ Wh,
             unsigned short* __restrict__ Wl)
{
    __shared__ float tile[32][33];
    const int k0 = blockIdx.x * 32, n0 = blockIdx.y * 32;
    const int tx = threadIdx.x, ty = threadIdx.y;
    const int n = n0 + tx, k = k0 + ty;
    tile[ty][tx] = (n < N_COLS) ? W[(size_t)k * N_COLS + n] : 0.f;
    __syncthreads();
    const float w = tile[tx][ty];           // = W[k0+tx][n0+ty]
    unsigned short h, l;
    split2(w, h, l);
    const size_t o = (size_t)(n0 + ty) * K_DIM + k0 + tx;
    Wh[o] = h; Wl[o] = l;
}

// ---------------- A: split fp32 chunk -> hi/lo bf16 (same layout) ----------------
__global__ __launch_bounds__(256)
void split_a(const float* __restrict__ x, unsigned short* __restrict__ Ah,
             unsigned short* __restrict__ Al, long long nelem)
{
    const long long i = ((long long)blockIdx.x * 256 + threadIdx.x) * 4;
    if (i >= nelem) return;
    const float4 v = *(const float4*)(x + i);
    unsigned short h0, h1, h2, h3, l0, l1, l2, l3;
    split2(v.x, h0, l0); split2(v.y, h1, l1);
    split2(v.z, h2, l2); split2(v.w, h3, l3);
    ushort4 hv = {h0, h1, h2, h3}, lv = {l0, l1, l2, l3};
    *(ushort4*)(Ah + i) = hv;
    *(ushort4*)(Al + i) = lv;
}

// ------------- GEMM: logits = A @ Wt^T + b via bf16 split-2 MFMA -------------
// 128x128 block tile, 256 thr = 4 waves each 64x64, 16x16x32 MFMA, BK=32.
// 1-D grid with XCD swizzle: xcd = bid&7 owns a contiguous band of m-strips,
// so the 8 blocks sharing an A-strip are co-resident on ONE XCD's L2.
__global__ __launch_bounds__(256, 4)
void gemm_mfma(const unsigned short* __restrict__ Ah, const unsigned short* __restrict__ Al,
               const unsigned short* __restrict__ Bh, const unsigned short* __restrict__ Bl,
               const float* __restrict__ bias, float* __restrict__ logits,
               int m_tiles)
{
    __shared__ short sAh[128 * 32];
    __shared__ short sAl[128 * 32];
    __shared__ short sBh[128 * 32];
    __shared__ short sBl[128 * 32];

    const int t = threadIdx.x;
    const int lane = t & 63;
    const int wave = t >> 6;
    const int ml = lane & 15;          // m (or n) within 16-tile
    const int half = lane >> 4;        // 0..3 -> k-quarter of 32
    const int wm = (wave >> 1) * 64, wn = (wave & 1) * 64;

    // ---- XCD swizzle (m_tiles divisible by 8; N_TILES == 8) ----
    const int bid  = blockIdx.x;
    const int xcd  = bid & 7;
    const int slot = bid >> 3;
    const int mt   = xcd * (m_tiles >> 3) + (slot >> 3);
    const int nt   = slot & 7;
    const int n0 = nt * 128;
    const int m0 = mt * 128;

    v4f acc[4][4];
#pragma unroll
    for (int i = 0; i < 4; ++i)
#pragma unroll
        for (int j = 0; j < 4; ++j) acc[i][j] = (v4f){0.f, 0.f, 0.f, 0.f};

    // staging map: lds byte t*16 (+4096) -> row r0(+64), byte-in-row kb0
    const int r0 = t >> 2;
    const int kb0 = (t & 3) * 16;
    const char* pAh = (const char*)Ah + (size_t)(m0 + r0) * (K_DIM * 2) + kb0;
    const char* pAl = (const char*)Al + (size_t)(m0 + r0) * (K_DIM * 2) + kb0;
    const char* pBh = (const char*)Bh + (size_t)(n0 + r0) * (K_DIM * 2) + kb0;
    const char* pBl = (const char*)Bl + (size_t)(n0 + r0) * (K_DIM * 2) + kb0;
    short* lAh = sAh + t * 8;  short* lAl = sAl + t * 8;
    short* lBh = sBh + t * 8;  short* lBl = sBl + t * 8;
    const size_t rstep = (size_t)64 * K_DIM * 2;   // +64 rows in bytes

    for (int kb = 0; kb < K_DIM * 2; kb += 64) {   // 32 k-values = 64 bytes / step
        GL_LDS16(pAh + kb, lAh);  GL_LDS16(pAh + rstep + kb, lAh + 2048);
        GL_LDS16(pAl + kb, lAl);  GL_LDS16(pAl + rstep + kb, lAl + 2048);
        GL_LDS16(pBh + kb, lBh);  GL_LDS16(pBh + rstep + kb, lBh + 2048);
        GL_LDS16(pBl + kb, lBl);  GL_LDS16(pBl + rstep + kb, lBl + 2048);
        __syncthreads();

        short8 ah[4], al[4], bh[4], bl[4];
#pragma unroll
        for (int i = 0; i < 4; ++i) {
            ah[i] = *(const short8*)&sAh[(wm + i * 16 + ml) * 32 + half * 8];
            al[i] = *(const short8*)&sAl[(wm + i * 16 + ml) * 32 + half * 8];
            bh[i] = *(const short8*)&sBh[(wn + i * 16 + ml) * 32 + half * 8];
            bl[i] = *(const short8*)&sBl[(wn + i * 16 + ml) * 32 + half * 8];
        }
#pragma unroll
        for (int i = 0; i < 4; ++i)
#pragma unroll
            for (int j = 0; j < 4; ++j) {
                acc[i][j] = __builtin_amdgcn_mfma_f32_16x16x32_bf16(ah[i], bl[j], acc[i][j], 0, 0, 0);
                acc[i][j] = __builtin_amdgcn_mfma_f32_16x16x32_bf16(al[i], bh[j], acc[i][j], 0, 0, 0);
                acc[i][j] = __builtin_amdgcn_mfma_f32_16x16x32_bf16(ah[i], bh[j], acc[i][j], 0, 0, 0);
            }
        __syncthreads();
    }

    // epilogue: C/D layout col = lane&15, row = (lane>>4)*4 + reg  [m89/m91]
#pragma unroll
    for (int i = 0; i < 4; ++i) {
        const int rbase = m0 + wm + i * 16 + half * 4;
#pragma unroll
        for (int j = 0; j < 4; ++j) {
            const int col = n0 + wn + j * 16 + ml;
            if (col < N_COLS) {
                const float bv = bias[col];
#pragma unroll
                for (int r = 0; r < 4; ++r)
                    logits[(size_t)(rbase + r) * N_COLS + col] = acc[i][j][r] + bv;
            }
        }
    }
}

// ------------- per-view softmax stats: entropy (f64 accum) + argmax -------------
__global__ __launch_bounds__(256)
void row_stats(const float* __restrict__ logits, double* __restrict__ ent,
               int* __restrict__ votes, int v_base)
{
    __shared__ float  srow[N_COLS];
    __shared__ float  redv[256];
    __shared__ int    redi[256];
    __shared__ double redS[256];
    __shared__ double redT[256];

    const int t = threadIdx.x;
    const float* row = logits + (size_t)blockIdx.x * N_COLS;

    float bv = -3.0e38f;
    int bi = 0;
    for (int c = t; c < N_COLS; c += 256) {
        const float x = row[c];
        srow[c] = x;
        if (x > bv) { bv = x; bi = c; }
    }
    redv[t] = bv; redi[t] = bi;
    __syncthreads();
    for (int s = 128; s > 0; s >>= 1) {
        if (t < s) {
            const float ov = redv[t + s]; const int oi = redi[t + s];
            if (ov > redv[t] || (ov == redv[t] && oi < redi[t])) { redv[t] = ov; redi[t] = oi; }
        }
        __syncthreads();
    }
    const float mx = redv[0];
    const int amax = redi[0];

    double S = 0.0, T = 0.0;
    for (int c = t; c < N_COLS; c += 256) {
        const float d = srow[c] - mx;
        const double e = exp((double)d);
        S += e; T += e * (double)d;
    }
    redS[t] = S; redT[t] = T;
    __syncthreads();
    for (int s = 128; s > 0; s >>= 1) {
        if (t < s) { redS[t] += redS[t + s]; redT[t] += redT[t + s]; }
        __syncthreads();
    }
    if (t == 0) {
        const double Sf = redS[0], Tf = redT[0];
        ent[v_base + blockIdx.x]   = log(Sf) - Tf / Sf;
        votes[v_base + blockIdx.x] = amax;
    }
}

// ------------- per-batch voting: stable sort by entropy, tie loop -------------
__global__ __launch_bounds__(64)
void vote_kernel(const double* __restrict__ ent, const int* __restrict__ votes,
                 float* __restrict__ out)
{
    __shared__ double e[NUM_TTA];
    __shared__ int    sv[NUM_TTA];
    __shared__ float  counts[N_COLS];

    const int b = blockIdx.x;
    const int t = threadIdx.x;

    e[t] = ent[b * NUM_TTA + t];
    const int myv = votes[b * NUM_TTA + t];
    for (int c = t; c < N_COLS; c += NUM_TTA) counts[c] = 0.f;
    __syncthreads();

    const double et = e[t];
    int rank = 0;
#pragma unroll
    for (int i = 0; i < NUM_TTA; ++i) {
        const double ei = e[i];
        rank += (ei < et) || (ei == et && i < t);
    }
    sv[rank] = myv;
    __syncthreads();

    if (t == 0) {
        for (int j = 0; j < KEPT; ++j) counts[sv[j]] += 1.f;
        float Mv = 0.f; int Tc = 0;
        for (int j = 0; j < KEPT; ++j) {
            const int c = sv[j];
            bool dup = false;
            for (int q = 0; q < j; ++q) dup = dup || (sv[q] == c);
            if (dup) continue;
            const float cv = counts[c];
            if (cv > Mv) { Mv = cv; Tc = 1; }
            else if (cv == Mv) { Tc += 1; }
        }
        for (int i = 0; i < NUM_TTA - KEPT; ++i) {
            if (Tc <= 1) break;
            const int c = sv[KEPT + i];
            const float oldc = counts[c];
            counts[c] = oldc + 1.f;
            if (oldc == Mv)            { Mv += 1.f; Tc = 1; }
            else if (oldc + 1.f == Mv) { Tc += 1; }
        }
    }
    __syncthreads();

    const size_t o0 = (size_t)b * N_COLS;
    for (int c = t; c < N_COLS; c += NUM_TTA)
        out[o0 + c] = logf(counts[c] * (1.f / 64.f) + 1e-8f);
}

// -------------------------------- launch --------------------------------
extern "C" void kernel_launch(void* const* d_in, const int* in_sizes, int n_in,
                              void* d_out, int out_size, void* d_ws, size_t ws_size,
                              hipStream_t stream) {
    const float* x    = (const float*)d_in[0];
    const float* Wm   = (const float*)d_in[1];
    const float* bias = (const float*)d_in[2];
    float* out = (float*)d_out;

    // ws layout: ent f64[16384] | votes i32[16384] | Wh,Wl bf16[1024*4096]
    //            | per-chunk: Ah,Al bf16[R*4096], logits f32[R*1000]
    char* p = (char*)d_ws;
    double* ent  = (double*)p;                     p += (size_t)M_ROWS * 8;
    int*   votes = (int*)p;                        p += (size_t)M_ROWS * 4;
    unsigned short* Wh = (unsigned short*)p;       p += (size_t)N_PAD * K_DIM * 2;
    unsigned short* Wl = (unsigned short*)p;       p += (size_t)N_PAD * K_DIM * 2;
    const size_t base = (size_t)(p - (char*)d_ws);

    // R: rows per chunk, multiple of 1024 so m_tiles is divisible by 8
    long long R = 0;
    if (ws_size > base) R = (long long)((ws_size - base) / (size_t)(8192 + 8192 + 4000));
    R = (R / 1024) * 1024;
    if (R > CHUNK_MAX) R = CHUNK_MAX;
    if (R < 1024) R = 1024;   // ws known >= ~184 MB from R2's behavior

    unsigned short* Ah = (unsigned short*)p;
    unsigned short* Al = Ah + (size_t)R * K_DIM;
    float* logits = (float*)(Al + (size_t)R * K_DIM);

    split_w<<<dim3(K_DIM / 32, N_PAD / 32), dim3(32, 32), 0, stream>>>(Wm, Wh, Wl);

    for (int m0 = 0; m0 < M_ROWS; m0 += (int)R) {
        const int rows = (int)(((long long)(M_ROWS - m0) < R) ? (M_ROWS - m0) : R);
        const int m_tiles = rows / 128;
        const long long nel = (long long)rows * K_DIM;
        split_a<<<(int)((nel / 4 + 255) / 256), 256, 0, stream>>>(
            x + (size_t)m0 * K_DIM, Ah, Al, nel);
        gemm_mfma<<<N_TILES * m_tiles, 256, 0, stream>>>(
            Ah, Al, Wh, Wl, bias, logits, m_tiles);
        row_stats<<<rows, 256, 0, stream>>>(logits, ent, votes, m0);
    }
    vote_kernel<<<BATCH, NUM_TTA, 0, stream>>>(ent, votes, out);
}